// Round 1
// baseline (5819.318 us; speedup 1.0000x reference)
//
#include <hip/hip_runtime.h>
#include <hip/hip_bf16.h>
#include <math.h>

// Shapes (VisualLlamaBlock): B=2, S=1024, H=2048, NH=16, HD=128, I=8192, V=1024, L=576
static constexpr int Hdim = 2048;
static constexpr int NHd  = 16;
static constexpr int HDd  = 128;
static constexpr int Bb   = 2;
static constexpr int Ss   = 1024;
static constexpr int Ii   = 8192;
static constexpr int Vv   = 1024;
static constexpr int Ll   = 576;

__device__ __forceinline__ float gelu_f(float x) {
    return 0.5f * x * (1.0f + tanhf(0.7978845608028654f * (x + 0.044715f * x * x * x)));
}
__device__ __forceinline__ float sigm_f(float x) { return 1.0f / (1.0f + expf(-x)); }

// ---------------- LayerNorm: one block per row of 2048 ----------------
__global__ __launch_bounds__(256) void ln_kernel(const float* __restrict__ x,
        const float* __restrict__ w, const float* __restrict__ b,
        float* __restrict__ out)
{
    const int row = blockIdx.x;
    const int tid = threadIdx.x;
    const float* xr = x + (size_t)row * Hdim;
    float v[8];
    const float4 t0 = *(const float4*)(xr + tid * 8);
    const float4 t1 = *(const float4*)(xr + tid * 8 + 4);
    v[0]=t0.x; v[1]=t0.y; v[2]=t0.z; v[3]=t0.w; v[4]=t1.x; v[5]=t1.y; v[6]=t1.z; v[7]=t1.w;
    float s = 0.f, sq = 0.f;
    #pragma unroll
    for (int i = 0; i < 8; ++i) { s += v[i]; sq += v[i] * v[i]; }
    #pragma unroll
    for (int m = 32; m >= 1; m >>= 1) { s += __shfl_xor(s, m, 64); sq += __shfl_xor(sq, m, 64); }
    __shared__ float ls[4], lq[4];
    const int wv = tid >> 6, ln = tid & 63;
    if (ln == 0) { ls[wv] = s; lq[wv] = sq; }
    __syncthreads();
    s  = ls[0] + ls[1] + ls[2] + ls[3];
    sq = lq[0] + lq[1] + lq[2] + lq[3];
    const float mean = s * (1.f / Hdim);
    const float var  = sq * (1.f / Hdim) - mean * mean;
    const float inv  = rsqrtf(var + 1e-6f);
    float o[8];
    #pragma unroll
    for (int i = 0; i < 8; ++i) { const int c = tid * 8 + i; o[i] = w[c] * (v[i] - mean) * inv + b[c]; }
    *(float4*)(out + (size_t)row * Hdim + tid * 8)     = make_float4(o[0], o[1], o[2], o[3]);
    *(float4*)(out + (size_t)row * Hdim + tid * 8 + 4) = make_float4(o[4], o[5], o[6], o[7]);
}

// ---------------- RoPE in-place on q and k ----------------
// thread -> (row = b*S+s, head, j<64); pairs (j, j+64), angle = s * 10000^(-j/64)
__global__ __launch_bounds__(256) void rope_kernel(float* __restrict__ q, float* __restrict__ k)
{
    const int idx  = blockIdx.x * 256 + threadIdx.x;
    const int j    = idx & 63;
    const int head = (idx >> 6) & (NHd - 1);
    const int row  = idx >> 10;
    const int s    = row & (Ss - 1);
    // match reference: inv_freq rounded to f32, angle rounded to f32, then exact cos/sin
    const float invf = (float)pow(10000.0, -(double)(2 * j) / 128.0);
    const float ang  = (float)s * invf;
    const double da  = (double)ang;
    const float c  = (float)cos(da);
    const float sn = (float)sin(da);
    const size_t base = (size_t)row * Hdim + head * HDd;
    float x1 = q[base + j], x2 = q[base + j + 64];
    q[base + j]      = x1 * c - x2 * sn;
    q[base + j + 64] = x2 * c + x1 * sn;
    x1 = k[base + j]; x2 = k[base + j + 64];
    k[base + j]      = x1 * c - x2 * sn;
    k[base + j + 64] = x2 * c + x1 * sn;
}

// ---------------- fp32 tiled GEMM, 128x128x16, 8x8 per thread ----------------
// TRANSB=1: B is [N,K] row-major (C = A * B^T).  TRANSB=0: B is [K,N] row-major.
// MODE 0: out = acc (+Cin)(+bias)
// MODE 1: out = E0 + acc
// MODE 2: out = gelu(E0) * acc
// MODE 3: out = E0 + sigmoid(acc + Cin + bias) * E1
#define BSPH(n) ((n) + ((((n) >> 5)) << 2))   // bank-skew for Bs columns

template<int TRANSB, int MODE>
__global__ __launch_bounds__(256) void gemm_kernel(
    const float* __restrict__ A, int lda,
    const float* __restrict__ Bm, int ldb,
    const float* __restrict__ bias,
    const float* __restrict__ Cin,
    const float* __restrict__ E0,
    const float* __restrict__ E1,
    float* __restrict__ outp, int ldo,
    int M, int N, int K)
{
    __shared__ float As[16][132];
    __shared__ float Bs[16][140];
    const int tid = threadIdx.x;
    const int tx = tid & 15, ty = tid >> 4;
    const int m0 = blockIdx.y * 128, n0 = blockIdx.x * 128;
    const int ar = tid >> 2, ac = (tid & 3) << 2;
    float acc[8][8] = {};

    for (int k0 = 0; k0 < K; k0 += 16) {
        #pragma unroll
        for (int r = 0; r < 2; ++r) {
            const int row = ar + (r << 6);
            const float4 av = *(const float4*)(A + (size_t)(m0 + row) * lda + (k0 + ac));
            As[ac + 0][row] = av.x; As[ac + 1][row] = av.y;
            As[ac + 2][row] = av.z; As[ac + 3][row] = av.w;
        }
        if (TRANSB) {
            #pragma unroll
            for (int r = 0; r < 2; ++r) {
                const int row = ar + (r << 6);   // n index
                const float4 bv = *(const float4*)(Bm + (size_t)(n0 + row) * ldb + (k0 + ac));
                const int pr = BSPH(row);
                Bs[ac + 0][pr] = bv.x; Bs[ac + 1][pr] = bv.y;
                Bs[ac + 2][pr] = bv.z; Bs[ac + 3][pr] = bv.w;
            }
        } else {
            #pragma unroll
            for (int r = 0; r < 2; ++r) {
                const int idx = tid + (r << 8);
                const int kk = idx >> 5, nn = (idx & 31) << 2;
                const float4 bv = *(const float4*)(Bm + (size_t)(k0 + kk) * ldb + (n0 + nn));
                *(float4*)&Bs[kk][BSPH(nn)] = bv;
            }
        }
        __syncthreads();
        #pragma unroll
        for (int kk = 0; kk < 16; ++kk) {
            const float4 a0 = *(const float4*)&As[kk][ty * 8];
            const float4 a1 = *(const float4*)&As[kk][ty * 8 + 4];
            const int bp = BSPH(tx * 8);
            const float4 b0 = *(const float4*)&Bs[kk][bp];
            const float4 b1 = *(const float4*)&Bs[kk][bp + 4];
            const float a[8] = {a0.x, a0.y, a0.z, a0.w, a1.x, a1.y, a1.z, a1.w};
            const float b[8] = {b0.x, b0.y, b0.z, b0.w, b1.x, b1.y, b1.z, b1.w};
            #pragma unroll
            for (int i = 0; i < 8; ++i)
                #pragma unroll
                for (int jj = 0; jj < 8; ++jj)
                    acc[i][jj] = fmaf(a[i], b[jj], acc[i][jj]);
        }
        __syncthreads();
    }

    #pragma unroll
    for (int i = 0; i < 8; ++i) {
        const int r = m0 + ty * 8 + i;
        #pragma unroll
        for (int j0 = 0; j0 < 8; j0 += 4) {
            const int c = n0 + tx * 8 + j0;
            const size_t off = (size_t)r * ldo + c;
            float vv[4] = {acc[i][j0], acc[i][j0 + 1], acc[i][j0 + 2], acc[i][j0 + 3]};
            if (Cin) {
                const float4 q4 = *(const float4*)(Cin + off);
                vv[0] += q4.x; vv[1] += q4.y; vv[2] += q4.z; vv[3] += q4.w;
            }
            if (bias) {
                const float4 q4 = *(const float4*)(bias + c);
                vv[0] += q4.x; vv[1] += q4.y; vv[2] += q4.z; vv[3] += q4.w;
            }
            if (MODE == 1) {
                const float4 e = *(const float4*)(E0 + off);
                vv[0] += e.x; vv[1] += e.y; vv[2] += e.z; vv[3] += e.w;
            } else if (MODE == 2) {
                const float4 e = *(const float4*)(E0 + off);
                vv[0] = gelu_f(e.x) * vv[0]; vv[1] = gelu_f(e.y) * vv[1];
                vv[2] = gelu_f(e.z) * vv[2]; vv[3] = gelu_f(e.w) * vv[3];
            } else if (MODE == 3) {
                const float4 e0 = *(const float4*)(E0 + off);
                const float4 e1 = *(const float4*)(E1 + off);
                vv[0] = e0.x + sigm_f(vv[0]) * e1.x; vv[1] = e0.y + sigm_f(vv[1]) * e1.y;
                vv[2] = e0.z + sigm_f(vv[2]) * e1.z; vv[3] = e0.w + sigm_f(vv[3]) * e1.w;
            }
            *(float4*)(outp + off) = make_float4(vv[0], vv[1], vv[2], vv[3]);
        }
    }
}

// ---------------- streaming-softmax attention (fp32) ----------------
// Q [B,qlen,H], K/V [B,klen,H] (head-interleaved), out [B,qlen,H].
// Block: 256 threads, 32 q-rows, KV tiles of 32. thread t -> (row i=t/8, group jg=t%8).
// Score columns per thread: j = jg + 8*jj (bank-conflict-free K reads).
template<int CAUSAL>
__global__ __launch_bounds__(256) void attn_kernel(
    const float* __restrict__ Qp, const float* __restrict__ Kp, const float* __restrict__ Vp,
    float* __restrict__ Op, int qlen, int klen, float scale)
{
    __shared__ float Qs[32][132];
    __shared__ float Ks[32][132];
    __shared__ float Vs[32][160];   // chunk-skewed: chunk ch (16 floats) at ch*20
    const int tid  = threadIdx.x;
    const int b    = blockIdx.z, head = blockIdx.y;
    const int q0   = blockIdx.x << 5;
    const size_t qbase = ((size_t)b * qlen) * Hdim + head * HDd;
    const size_t kbase = ((size_t)b * klen) * Hdim + head * HDd;

    #pragma unroll
    for (int r = 0; r < 4; ++r) {
        const int idx = tid + (r << 8);
        const int row = idx >> 5, c4 = (idx & 31) << 2;
        *(float4*)&Qs[row][c4] = *(const float4*)(Qp + qbase + (size_t)(q0 + row) * Hdim + c4);
    }
    const int i  = tid >> 3;
    const int jg = tid & 7;
    const int d0 = jg << 4;
    const int vp0 = jg * 20;
    const int lbase = (tid & 63) & ~7;
    float o[16] = {};
    float mi = -1e30f, li = 0.f;
    const int nt = CAUSAL ? ((int)blockIdx.x + 1) : (klen >> 5);

    for (int kt = 0; kt < nt; ++kt) {
        const int kt0 = kt << 5;
        __syncthreads();   // Qs ready (first iter) / prev PV done before overwrite
        #pragma unroll
        for (int r = 0; r < 4; ++r) {
            const int idx = tid + (r << 8);
            const int row = idx >> 5, c4 = (idx & 31) << 2;
            *(float4*)&Ks[row][c4] = *(const float4*)(Kp + kbase + (size_t)(kt0 + row) * Hdim + c4);
            const int vc = c4 + ((c4 >> 4) << 2);
            *(float4*)&Vs[row][vc] = *(const float4*)(Vp + kbase + (size_t)(kt0 + row) * Hdim + c4);
        }
        __syncthreads();

        float s4[4] = {0.f, 0.f, 0.f, 0.f};
        #pragma unroll 8
        for (int d4 = 0; d4 < 32; ++d4) {
            const float4 qv = *(const float4*)&Qs[i][d4 << 2];
            #pragma unroll
            for (int jj = 0; jj < 4; ++jj) {
                const float4 kv = *(const float4*)&Ks[jg + (jj << 3)][d4 << 2];
                s4[jj] = fmaf(qv.x, kv.x, s4[jj]);
                s4[jj] = fmaf(qv.y, kv.y, s4[jj]);
                s4[jj] = fmaf(qv.z, kv.z, s4[jj]);
                s4[jj] = fmaf(qv.w, kv.w, s4[jj]);
            }
        }
        float mloc = -1e30f;
        #pragma unroll
        for (int jj = 0; jj < 4; ++jj) {
            s4[jj] *= scale;
            if (CAUSAL) { if (kt0 + jg + (jj << 3) > q0 + i) s4[jj] -= 1e4f; }
            mloc = fmaxf(mloc, s4[jj]);
        }
        #pragma unroll
        for (int m = 1; m < 8; m <<= 1) mloc = fmaxf(mloc, __shfl_xor(mloc, m, 64));
        const float mnew = fmaxf(mi, mloc);
        const float corr = expf(mi - mnew);
        float p4[4]; float ps = 0.f;
        #pragma unroll
        for (int jj = 0; jj < 4; ++jj) { p4[jj] = expf(s4[jj] - mnew); ps += p4[jj]; }
        #pragma unroll
        for (int m = 1; m < 8; m <<= 1) ps += __shfl_xor(ps, m, 64);
        li = li * corr + ps;
        mi = mnew;
        #pragma unroll
        for (int d = 0; d < 16; ++d) o[d] *= corr;
        #pragma unroll
        for (int j = 0; j < 32; ++j) {
            const float pj = __shfl(p4[j >> 3], lbase + (j & 7), 64);
            const float* vr = &Vs[j][vp0];
            const float4 v0 = *(const float4*)(vr);
            const float4 v1 = *(const float4*)(vr + 4);
            const float4 v2 = *(const float4*)(vr + 8);
            const float4 v3 = *(const float4*)(vr + 12);
            o[0]  = fmaf(pj, v0.x, o[0]);  o[1]  = fmaf(pj, v0.y, o[1]);
            o[2]  = fmaf(pj, v0.z, o[2]);  o[3]  = fmaf(pj, v0.w, o[3]);
            o[4]  = fmaf(pj, v1.x, o[4]);  o[5]  = fmaf(pj, v1.y, o[5]);
            o[6]  = fmaf(pj, v1.z, o[6]);  o[7]  = fmaf(pj, v1.w, o[7]);
            o[8]  = fmaf(pj, v2.x, o[8]);  o[9]  = fmaf(pj, v2.y, o[9]);
            o[10] = fmaf(pj, v2.z, o[10]); o[11] = fmaf(pj, v2.w, o[11]);
            o[12] = fmaf(pj, v3.x, o[12]); o[13] = fmaf(pj, v3.y, o[13]);
            o[14] = fmaf(pj, v3.z, o[14]); o[15] = fmaf(pj, v3.w, o[15]);
        }
    }
    const float inv = 1.0f / li;
    const size_t ob = qbase + (size_t)(q0 + i) * Hdim + d0;
    *(float4*)(Op + ob)      = make_float4(o[0]*inv,  o[1]*inv,  o[2]*inv,  o[3]*inv);
    *(float4*)(Op + ob + 4)  = make_float4(o[4]*inv,  o[5]*inv,  o[6]*inv,  o[7]*inv);
    *(float4*)(Op + ob + 8)  = make_float4(o[8]*inv,  o[9]*inv,  o[10]*inv, o[11]*inv);
    *(float4*)(Op + ob + 12) = make_float4(o[12]*inv, o[13]*inv, o[14]*inv, o[15]*inv);
}

// ---------------- host ----------------
extern "C" void kernel_launch(void* const* d_in, const int* in_sizes, int n_in,
                              void* d_out, int out_size, void* d_ws, size_t ws_size,
                              hipStream_t stream)
{
    const float* hidden  = (const float*)d_in[0];
    const float* encin   = (const float*)d_in[1];
    // d_in[2] attention_mask: causal -1e4, applied analytically in attn_kernel
    const float* wq      = (const float*)d_in[3];
    const float* wk      = (const float*)d_in[4];
    const float* wv      = (const float*)d_in[5];
    const float* wo      = (const float*)d_in[6];
    const float* cattn_w = (const float*)d_in[7];
    const float* cattn_b = (const float*)d_in[8];
    const float* cproj_w = (const float*)d_in[9];
    const float* cproj_b = (const float*)d_in[10];
    const float* vis_w   = (const float*)d_in[11];
    const float* vis_b   = (const float*)d_in[12];
    const float* gate_w  = (const float*)d_in[13];
    const float* up_w    = (const float*)d_in[14];
    const float* down_w  = (const float*)d_in[15];
    const float* ln1w    = (const float*)d_in[16];
    const float* ln1b    = (const float*)d_in[17];
    const float* ln2w    = (const float*)d_in[18];
    const float* ln2b    = (const float*)d_in[19];
    const float* fca_w   = (const float*)d_in[20];
    const float* fca_b   = (const float*)d_in[21];
    float* out = (float*)d_out;

    float* ws = (float*)d_ws;
    const size_t SZ = (size_t)Bb * Ss * Hdim;   // 4,194,304 floats (16 MB)
    float* buf_h   = ws;              // LN out (h, later h2)
    float* buf_q   = ws + SZ;         // q -> cq -> alpha-tmp
    float* buf_k   = ws + 2 * SZ;     // k -> hs2
    float* buf_v   = ws + 3 * SZ;     // v   (phase A)
    float* buf_hs  = ws + 4 * SZ;     // hs  (phase A)
    float* buf_t1  = ws + 5 * SZ;     // attn_out / cross_pre (phase A)
    float* buf_t2  = ws + 6 * SZ;     // cross (phase A)
    float* buf_enc = ws + 7 * SZ;     // enc [2*576*2048]
    float* buf_g   = ws + 3 * SZ;     // gate / gate*up (phase B, aliases v..t2)
    // peak ws use: (7*SZ + 2,359,296) floats = ~121 MB

    const float scale = 0.08838834764831845f;  // 1/sqrt(128)
    const dim3 blk(256);

    // 1. h = LN1(hidden)
    ln_kernel<<<dim3(Bb * Ss), blk, 0, stream>>>(hidden, ln1w, ln1b, buf_h);
    // 2. q,k,v = h @ {wq,wk,wv}^T
    gemm_kernel<1,0><<<dim3(16,16), blk, 0, stream>>>(buf_h, Hdim, wq, Hdim, nullptr, nullptr, nullptr, nullptr, buf_q, Hdim, 2048, 2048, 2048);
    gemm_kernel<1,0><<<dim3(16,16), blk, 0, stream>>>(buf_h, Hdim, wk, Hdim, nullptr, nullptr, nullptr, nullptr, buf_k, Hdim, 2048, 2048, 2048);
    gemm_kernel<1,0><<<dim3(16,16), blk, 0, stream>>>(buf_h, Hdim, wv, Hdim, nullptr, nullptr, nullptr, nullptr, buf_v, Hdim, 2048, 2048, 2048);
    // 3. RoPE(q,k)
    rope_kernel<<<dim3(8192), blk, 0, stream>>>(buf_q, buf_k);
    // 4. self-attention (causal)
    attn_kernel<1><<<dim3(32, NHd, Bb), blk, 0, stream>>>(buf_q, buf_k, buf_v, buf_t1, Ss, Ss, scale);
    // 5. hs = hidden + attn_out @ wo^T
    gemm_kernel<1,1><<<dim3(16,16), blk, 0, stream>>>(buf_t1, Hdim, wo, Hdim, nullptr, nullptr, hidden, nullptr, buf_hs, Hdim, 2048, 2048, 2048);
    // 6. cq = hs @ c_attn_w[:, :H] + c_attn_b[:H]   (only the query slice is used)
    gemm_kernel<0,0><<<dim3(16,16), blk, 0, stream>>>(buf_hs, Hdim, cattn_w, 3 * Hdim, cattn_b, nullptr, nullptr, nullptr, buf_q, Hdim, 2048, 2048, 2048);
    // 7. enc = encoder_output @ vis_w + vis_b   (M=1152, K=1024)
    gemm_kernel<0,0><<<dim3(16,9), blk, 0, stream>>>(encin, Vv, vis_w, Hdim, vis_b, nullptr, nullptr, nullptr, buf_enc, Hdim, Bb * Ll, 2048, Vv);
    // 8. cross-attention (no mask, klen=576)
    attn_kernel<0><<<dim3(32, NHd, Bb), blk, 0, stream>>>(buf_q, buf_enc, buf_enc, buf_t1, Ss, Ll, scale);
    // 9. cross = cross_pre @ c_proj_w + c_proj_b
    gemm_kernel<0,0><<<dim3(16,16), blk, 0, stream>>>(buf_t1, Hdim, cproj_w, Hdim, cproj_b, nullptr, nullptr, nullptr, buf_t2, Hdim, 2048, 2048, 2048);
    // 10. tmp = hs @ fc_alpha_w[:, :H]^T
    gemm_kernel<1,0><<<dim3(16,16), blk, 0, stream>>>(buf_hs, Hdim, fca_w, 2 * Hdim, nullptr, nullptr, nullptr, nullptr, buf_q, Hdim, 2048, 2048, 2048);
    // 11. hs2 = hs + sigmoid(tmp + cross @ fc_alpha_w[:, H:]^T + b) * cross
    gemm_kernel<1,3><<<dim3(16,16), blk, 0, stream>>>(buf_t2, Hdim, fca_w + Hdim, 2 * Hdim, fca_b, buf_q, buf_hs, buf_t2, buf_k, Hdim, 2048, 2048, 2048);
    // 12. h2 = LN2(hs2)
    ln_kernel<<<dim3(Bb * Ss), blk, 0, stream>>>(buf_k, ln2w, ln2b, buf_h);
    // 13. g = h2 @ gate_w^T
    gemm_kernel<1,0><<<dim3(64,16), blk, 0, stream>>>(buf_h, Hdim, gate_w, Hdim, nullptr, nullptr, nullptr, nullptr, buf_g, Ii, 2048, Ii, 2048);
    // 14. gu = gelu(g) * (h2 @ up_w^T)   (in-place over g: each element read-then-written by same thread)
    gemm_kernel<1,2><<<dim3(64,16), blk, 0, stream>>>(buf_h, Hdim, up_w, Hdim, nullptr, nullptr, buf_g, nullptr, buf_g, Ii, 2048, Ii, 2048);
    // 15. out = hs2 + gu @ down_w^T
    gemm_kernel<1,1><<<dim3(16,16), blk, 0, stream>>>(buf_g, Ii, down_w, Ii, nullptr, nullptr, buf_k, nullptr, out, Hdim, 2048, 2048, Ii);
}